// Round 7
// baseline (179.171 us; speedup 1.0000x reference)
//
#include <hip/hip_runtime.h>

// Problem constants
#define NB     64      // batch
#define TT     2048    // time
#define INQ    8       // input size
#define CC     2       // channels
#define MM     10      // hidden m
#define ROWP   12      // padded row floats (48 B)
#define MATS   124     // matrix stride in LDS tree (124%32=28)
#define SKST   12      // skq row stride floats (48 B, b128-aligned)
#define BLK    512     // threads per block (8 waves)
#define SEGS   96      // 8 waves * 12 five-lane groups
#define SLEN   11      // steps per segment (padded timeline 2112 = 2*96*11, 3% pad)
#define NCHK   2       // chunks per chain -> grid 256 = 1 block/CU
#define NCHAIN (NB*CC)

typedef float v2f __attribute__((ext_vector_type(2)));

static_assert(SLEN % 2 == 1, "pipeline assumes odd SLEN");

// Upper-triangle index for (k,j), k<j, into 45-element array
__device__ __forceinline__ constexpr int triIdx(int k, int j) {
    return k * 10 + j - ((k + 1) * (k + 2)) / 2;
}

// In-wave gather: pull value of register v from wave-lane (addr_bytes>>2).
__device__ __forceinline__ float bperm_f(int addr_bytes, float v) {
    return __int_as_float(__builtin_amdgcn_ds_bpermute(addr_bytes, __float_as_int(v)));
}

// One Taylor row-stream, packed pair of rows: t = S*G; A = t; R += cj*t.
// Row r of S*G depends only on row r of S -> in-place safe (S may alias A).
__device__ __forceinline__ void trow_pk(const float* __restrict__ Tri,
                                        v2f* A, v2f* R, const v2f* S, float cj) {
    v2f t[MM];
    t[0] = -S[1] * Tri[triIdx(0, 1)];
    #pragma unroll
    for (int j = 1; j < MM; ++j) t[j] = S[0] * Tri[triIdx(0, j)];
    #pragma unroll
    for (int k = 1; k < MM; ++k) {
        const v2f a = S[k];
        #pragma unroll
        for (int j = 0; j < MM; ++j) {
            if (k == j) continue;
            if (j == 0 && k == 1) continue;
            if (j > k) t[j] += a * Tri[triIdx(k, j)];
            else       t[j] -= a * Tri[triIdx(j, k)];
        }
    }
    #pragma unroll
    for (int j = 0; j < MM; ++j) { A[j] = t[j]; R[j] += cj * t[j]; }
}

// KTAY=5 Taylor burst on the packed row-pair accumulator.
__device__ __forceinline__ void taylor5(const float* __restrict__ Tri, v2f* R01) {
    __builtin_amdgcn_s_setprio(1);
    v2f A01[MM];
    trow_pk(Tri, A01, R01, R01, 1.0f);
    trow_pk(Tri, A01, R01, A01, 0.5f);
    trow_pk(Tri, A01, R01, A01, 0.16666667f);
    trow_pk(Tri, A01, R01, A01, 0.041666668f);
    trow_pk(Tri, A01, R01, A01, 0.0083333338f);
    __builtin_amdgcn_s_setprio(0);
}

// Assemble one step's Tri[45]: rotate x (cur <- nxt), dx, tvv (9 per-lane
// entries), then 45 in-wave bpermutes to broadcast the group's 45 entries.
// Independent of the Taylor recurrence -> pipelines ahead of it.
__device__ __forceinline__ void assemble_tri(const float4* __restrict__ px,
                                             int& tn, float4& cur0, float4& cur1,
                                             const float* __restrict__ srow,
                                             int base, float* __restrict__ Tri) {
    const int tc = (tn > TT - 1) ? TT - 1 : tn;
    const float4 b0 = px[2 * tc], b1 = px[2 * tc + 1];
    float dx[INQ];
    dx[0] = b0.x - cur0.x; dx[1] = b0.y - cur0.y;
    dx[2] = b0.z - cur0.z; dx[3] = b0.w - cur0.w;
    dx[4] = b1.x - cur1.x; dx[5] = b1.y - cur1.y;
    dx[6] = b1.z - cur1.z; dx[7] = b1.w - cur1.w;
    cur0 = b0; cur1 = b1; ++tn;

    float tvv[9];
    #pragma unroll
    for (int i = 0; i < 9; ++i) {
        const float4 s0 = *reinterpret_cast<const float4*>(srow + i * SKST);
        const float4 s1 = *reinterpret_cast<const float4*>(srow + i * SKST + 4);
        tvv[i] = dx[0] * s0.x + dx[1] * s0.y + dx[2] * s0.z + dx[3] * s0.w
               + dx[4] * s1.x + dx[5] * s1.y + dx[6] * s1.z + dx[7] * s1.w;
    }
    #pragma unroll
    for (int e = 0; e < 45; ++e)
        Tri[e] = bperm_f(base + (e / 9) * 4, tvv[e % 9]);
}

// 2-lane pair combine: buf[ls] <- buf[ls] * buf[rs] (pq = which 5-row half)
__device__ __forceinline__ void pair_combine(float* buf_s, int ls, int rs, int pq) {
    float lrow[5][MM];
    #pragma unroll
    for (int r = 0; r < 5; ++r) {
        const float4* lr = reinterpret_cast<const float4*>(
            &buf_s[ls * MATS + (pq * 5 + r) * ROWP]);
        const float4 a = lr[0], b = lr[1], c4 = lr[2];
        lrow[r][0] = a.x;  lrow[r][1] = a.y;  lrow[r][2] = a.z;  lrow[r][3] = a.w;
        lrow[r][4] = b.x;  lrow[r][5] = b.y;  lrow[r][6] = b.z;  lrow[r][7] = b.w;
        lrow[r][8] = c4.x; lrow[r][9] = c4.y;
    }
    float d[5][MM];
    #pragma unroll
    for (int r = 0; r < 5; ++r)
        #pragma unroll
        for (int j = 0; j < MM; ++j)
            d[r][j] = 0.0f;
    #pragma unroll
    for (int k = 0; k < MM; ++k) {
        const float4* rr = reinterpret_cast<const float4*>(&buf_s[rs * MATS + k * ROWP]);
        const float4 a = rr[0], b = rr[1], c4 = rr[2];
        float rrow[MM];
        rrow[0] = a.x;  rrow[1] = a.y;  rrow[2] = a.z;  rrow[3] = a.w;
        rrow[4] = b.x;  rrow[5] = b.y;  rrow[6] = b.z;  rrow[7] = b.w;
        rrow[8] = c4.x; rrow[9] = c4.y;
        #pragma unroll
        for (int r = 0; r < 5; ++r) {
            const float lv = lrow[r][k];
            #pragma unroll
            for (int j = 0; j < MM; ++j)
                d[r][j] += lv * rrow[j];
        }
    }
    float* dst = &buf_s[ls * MATS + pq * 5 * ROWP];
    #pragma unroll
    for (int r = 0; r < 5; ++r) {
        float4* drow = reinterpret_cast<float4*>(dst + r * ROWP);
        drow[0] = make_float4(d[r][0], d[r][1], d[r][2], d[r][3]);
        drow[1] = make_float4(d[r][4], d[r][5], d[r][6], d[r][7]);
        drow[2] = make_float4(d[r][8], d[r][9], 0.0f, 0.0f);
    }
}

// r19: in-wave software pipeline. r12/r17/r18 all pin dev_serial at ~61 us
// while VALUBusy drifts 49->43->37%: busy-time tracks work, wall-clock
// doesn't -> latency-bound on the per-step chain x-load -> tvv -> 45 bperm
// -> Taylor, and occupancy can't fill it (waves stall in lockstep; r17's
// 2x waves bought nothing). Fix: 2-stage Tri double-buffer (TriA/TriB,
// even/odd unrolled - static indexing only, no runtime-indexed regs).
// Assembly of step s+1 issues BEFORE the ~550-FMA Taylor of step s, so
// LDS/global latency hides under compute. SLEN=11 pipelines cleanly:
// prologue assembles step 0; 5x {asm s+1; tay s; asm s+2; tay s+1};
// epilogue tay step 10. x rotation restored (cur<-nxt, halves x loads).
// VGPR est ~185-210 < 256 cap at (512,1) -> 2 waves/SIMD, no spill
// (litmus: FETCH ~4.25 MB, WRITE ~120 KB). Math bit-identical per step.
__global__ __launch_bounds__(BLK, 1)
void dev_serial(const float* __restrict__ x,
                const float* __restrict__ A,
                float* __restrict__ ws)
{
    __shared__ __align__(16) float skq_s[45 * SKST];    // 2160 B, e-major
    __shared__ __align__(16) float buf_s[SEGS * MATS];  // 47616 B tree buffer

    const int tid   = threadIdx.x;
    const int chain = blockIdx.x >> 1;   // / NCHK
    const int qt    = blockIdx.x & 1;
    const int n     = chain >> 1;        // / CC
    const int c     = chain & 1;

    // skq[e][ip] = sk-tri entry e of input dim ip (channel c). 360 entries.
    if (tid < 45 * 8) {
        const int e  = tid >> 3;
        const int ip = tid & 7;
        int k = 0, r2 = e;
        while (r2 >= 9 - k) { r2 -= (9 - k); ++k; }
        const int j = k + 1 + r2;
        const float* Ab = A + (size_t)(c * INQ + ip) * (MM * MM);
        skq_s[e * SKST + ip] = Ab[k * MM + j] - Ab[j * MM + k];
    }
    __syncthreads();

    const int wv  = tid >> 6;            // wave 0..7
    const int wl  = tid & 63;            // lane in wave
    const int g   = wl / 5;              // group 0..11 (12 = inactive tail)
    const int r   = wl - 5 * g;          // role 0..4 -> owns rows {2r, 2r+1}
    const bool act = (wl < 60);
    const int seg = wv * 12 + g;         // 0..95 active (96+ = harmless)
    const int p0  = 2 * r;

    v2f R01[MM];
    #pragma unroll
    for (int j = 0; j < MM; ++j)
        R01[j] = (v2f){ (j == p0) ? 1.0f : 0.0f, (j == p0 + 1) ? 1.0f : 0.0f };

    const float4* px = reinterpret_cast<const float4*>(x + (size_t)n * TT * INQ);
    const int t0 = qt * (SEGS * SLEN) + seg * SLEN;   // padded timeline, < 2112
    const float* srow = &skq_s[(9 * r) * SKST];
    const int base = (wl - r) * 4;       // group-base byte address for bperm

    // Pipeline state: cur x, next time index, Tri double-buffer.
    float4 cur0, cur1;
    int tn = t0;
    {
        const int tc = (tn > TT - 1) ? TT - 1 : tn;
        cur0 = px[2 * tc]; cur1 = px[2 * tc + 1];
        ++tn;                            // first assemble loads t0+1
    }
    float TriA[45], TriB[45];
    assemble_tri(px, tn, cur0, cur1, srow, base, TriA);   // step 0

    #pragma unroll 1
    for (int it = 0; it < (SLEN - 1) / 2; ++it) {
        assemble_tri(px, tn, cur0, cur1, srow, base, TriB);  // step 2it+1
        taylor5(TriA, R01);                                   // step 2it
        assemble_tri(px, tn, cur0, cur1, srow, base, TriA);  // step 2it+2
        taylor5(TriB, R01);                                   // step 2it+1
    }
    taylor5(TriA, R01);                                       // step SLEN-1

    // Store segment product: each active lane stores its pair of rows.
    if (act) {
        float* dst = &buf_s[seg * MATS];
        float4* d0 = reinterpret_cast<float4*>(dst + p0 * ROWP);
        d0[0] = make_float4(R01[0].x, R01[1].x, R01[2].x, R01[3].x);
        d0[1] = make_float4(R01[4].x, R01[5].x, R01[6].x, R01[7].x);
        d0[2] = make_float4(R01[8].x, R01[9].x, 0.0f, 0.0f);
        float4* d1 = reinterpret_cast<float4*>(dst + (p0 + 1) * ROWP);
        d1[0] = make_float4(R01[0].y, R01[1].y, R01[2].y, R01[3].y);
        d1[1] = make_float4(R01[4].y, R01[5].y, R01[6].y, R01[7].y);
        d1[2] = make_float4(R01[8].y, R01[9].y, 0.0f, 0.0f);
    }
    __syncthreads();

    // Dyadic tree on 96 leaves: spans 2..32 -> products at {0,32,64},
    // then (0*32) and (0*64) sequential tail (time order preserved).
    #pragma unroll 1
    for (int span = 2; span <= 32; span <<= 1) {
        const int np = SEGS / span;
        if (tid < 2 * np) {
            const int pr = tid >> 1;
            const int pq = tid & 1;
            pair_combine(buf_s, pr * span, pr * span + (span >> 1), pq);
        }
        __syncthreads();
    }
    if (tid < 2) pair_combine(buf_s, 0, 32, tid);
    __syncthreads();
    if (tid < 2) pair_combine(buf_s, 0, 64, tid);
    __syncthreads();

    // Chunk product -> ws, padded 120 floats at (chain*NCHK + qt)
    if (tid < 30) {
        const float4 v = reinterpret_cast<const float4*>(buf_s)[tid];
        reinterpret_cast<float4*>(ws)[((size_t)chain * NCHK + qt) * 30 + tid] = v;
    }
}

// K2: one block per chain; combine its 2 chunk products (time order)
__global__ __launch_bounds__(256)
void dev_tree2(const float* __restrict__ ws, float* __restrict__ out)
{
    __shared__ __align__(16) float buf_s[2 * MATS];
    const int tid   = threadIdx.x;
    const int chain = blockIdx.x;

    if (tid < 60) {
        const int m  = tid / 30;
        const int o4 = tid - m * 30;
        const float4 v = reinterpret_cast<const float4*>(ws)[((size_t)chain * 2 + m) * 30 + o4];
        reinterpret_cast<float4*>(&buf_s[m * MATS])[o4] = v;
    }
    __syncthreads();

    if (tid < 2)
        pair_combine(buf_s, 0, 1, tid);
    __syncthreads();

    if (tid < 100) {
        const int i = tid / 10;
        const int j = tid - i * 10;
        out[(size_t)chain * 100 + tid] = buf_s[i * ROWP + j];
    }
}

extern "C" void kernel_launch(void* const* d_in, const int* in_sizes, int n_in,
                              void* d_out, int out_size, void* d_ws, size_t ws_size,
                              hipStream_t stream) {
    (void)in_sizes; (void)n_in; (void)out_size; (void)ws_size;
    const float* x = (const float*)d_in[0];  // (64, 2048, 8)
    const float* A = (const float*)d_in[1];  // (2, 8, 10, 10)
    float* out = (float*)d_out;              // (64, 2, 10, 10)
    float* ws  = (float*)d_ws;               // 256 mats * 480 B = 122,880 B

    dev_serial<<<dim3(NCHAIN * NCHK), dim3(BLK), 0, stream>>>(x, A, ws);
    dev_tree2<<<dim3(NCHAIN), dim3(256), 0, stream>>>(ws, out);
}

// Round 8
// 96.672 us; speedup vs baseline: 1.8534x; 1.8534x over previous
//
#include <hip/hip_runtime.h>

// Problem constants
#define NB     64      // batch
#define TT     2048    // time
#define INQ    8       // input size
#define CC     2       // channels
#define MM     10      // hidden m
#define ROWP   12      // padded row floats (48 B)
#define MATS   124     // matrix stride in LDS tree (124%32=28)
#define SKST   12      // skq row stride floats (48 B, b128-aligned)
#define BLK    512     // threads per block (8 waves)
#define SEGS   96      // 8 waves * 12 five-lane groups
#define SLEN   11      // steps per segment (padded timeline 2112 = 2*96*11, 3% pad)
#define NCHK   2       // chunks per chain -> grid 256 = 1 block/CU
#define NCHAIN (NB*CC)
#define SCRS   60      // scratch slot floats per group (5 lanes x 12)
#define FLAGS_OFF_F (NCHAIN * NCHK * 120)   // 30720 floats = 122,880 B

typedef float v2f __attribute__((ext_vector_type(2)));

// Upper-triangle index for (k,j), k<j, into 45-element array
__device__ __forceinline__ constexpr int triIdx(int k, int j) {
    return k * 10 + j - ((k + 1) * (k + 2)) / 2;
}

// One Taylor row-stream, packed pair of rows: t = S*G; A = t; R += cj*t.
// Row r of S*G depends only on row r of S -> in-place safe (S may alias A).
__device__ __forceinline__ void trow_pk(const float* __restrict__ Tri,
                                        v2f* A, v2f* R, const v2f* S, float cj) {
    v2f t[MM];
    t[0] = -S[1] * Tri[triIdx(0, 1)];
    #pragma unroll
    for (int j = 1; j < MM; ++j) t[j] = S[0] * Tri[triIdx(0, j)];
    #pragma unroll
    for (int k = 1; k < MM; ++k) {
        const v2f a = S[k];
        #pragma unroll
        for (int j = 0; j < MM; ++j) {
            if (k == j) continue;
            if (j == 0 && k == 1) continue;
            if (j > k) t[j] += a * Tri[triIdx(k, j)];
            else       t[j] -= a * Tri[triIdx(j, k)];
        }
    }
    #pragma unroll
    for (int j = 0; j < MM; ++j) { A[j] = t[j]; R[j] += cj * t[j]; }
}

// KTAY=5 Taylor burst on the packed row-pair accumulator.
__device__ __forceinline__ void taylor5(const float* __restrict__ Tri, v2f* R01) {
    __builtin_amdgcn_s_setprio(1);
    v2f A01[MM];
    trow_pk(Tri, A01, R01, R01, 1.0f);
    trow_pk(Tri, A01, R01, A01, 0.5f);
    trow_pk(Tri, A01, R01, A01, 0.16666667f);
    trow_pk(Tri, A01, R01, A01, 0.041666668f);
    trow_pk(Tri, A01, R01, A01, 0.0083333338f);
    __builtin_amdgcn_s_setprio(0);
}

// 2-lane pair combine: buf[ls] <- buf[ls] * buf[rs] (pq = which 5-row half)
__device__ __forceinline__ void pair_combine(float* buf_s, int ls, int rs, int pq) {
    float lrow[5][MM];
    #pragma unroll
    for (int r = 0; r < 5; ++r) {
        const float4* lr = reinterpret_cast<const float4*>(
            &buf_s[ls * MATS + (pq * 5 + r) * ROWP]);
        const float4 a = lr[0], b = lr[1], c4 = lr[2];
        lrow[r][0] = a.x;  lrow[r][1] = a.y;  lrow[r][2] = a.z;  lrow[r][3] = a.w;
        lrow[r][4] = b.x;  lrow[r][5] = b.y;  lrow[r][6] = b.z;  lrow[r][7] = b.w;
        lrow[r][8] = c4.x; lrow[r][9] = c4.y;
    }
    float d[5][MM];
    #pragma unroll
    for (int r = 0; r < 5; ++r)
        #pragma unroll
        for (int j = 0; j < MM; ++j)
            d[r][j] = 0.0f;
    #pragma unroll
    for (int k = 0; k < MM; ++k) {
        const float4* rr = reinterpret_cast<const float4*>(&buf_s[rs * MATS + k * ROWP]);
        const float4 a = rr[0], b = rr[1], c4 = rr[2];
        float rrow[MM];
        rrow[0] = a.x;  rrow[1] = a.y;  rrow[2] = a.z;  rrow[3] = a.w;
        rrow[4] = b.x;  rrow[5] = b.y;  rrow[6] = b.z;  rrow[7] = b.w;
        rrow[8] = c4.x; rrow[9] = c4.y;
        #pragma unroll
        for (int r = 0; r < 5; ++r) {
            const float lv = lrow[r][k];
            #pragma unroll
            for (int j = 0; j < MM; ++j)
                d[r][j] += lv * rrow[j];
        }
    }
    float* dst = &buf_s[ls * MATS + pq * 5 * ROWP];
    #pragma unroll
    for (int r = 0; r < 5; ++r) {
        float4* drow = reinterpret_cast<float4*>(dst + r * ROWP);
        drow[0] = make_float4(d[r][0], d[r][1], d[r][2], d[r][3]);
        drow[1] = make_float4(d[r][4], d[r][5], d[r][6], d[r][7]);
        drow[2] = make_float4(d[r][8], d[r][9], 0.0f, 0.0f);
    }
}

// r20: two cuts. (1) LDS-op diet: r18's 45 ds_bpermute + 18 b128/step/wave
// = 504 wave-LDS-ops/CU/step saturate the per-CU LDS crossbar (the per-step
// cost ~5-10k cyc >> ~1.2k cyc of VALU issue; r17 vs r18 algebra puts
// s ~ 2-4 us/step, latency/pipe-bound). Replace the bperm broadcast with a
// group scratch slot in LDS: each lane writes its 9 tvv (2 b128 + b32),
// reads the group's 45 back as 5x(b128,b128,b32) -> 36 ops/step/wave.
// Same-wave LDS ops execute in order -> no barrier, no hazard. Scratch
// (97 slots x 60 floats = 23 KB) overlays buf_s; one barrier before the
// tree store protects cross-wave reuse. Values bit-identical to r18.
// (2) K2 fusion: r18 total(97.3) - serial(61.5) = ~36 us for a trivial
// second kernel + launch gap. Each block atomically stores its 120-float
// chunk product to ws (AGENT scope, coherent across XCD L2s), bumps a
// per-chain flag; second arriver re-loads both chunks via AGENT-scope
// atomic loads, pair_combines, writes out. Flags zeroed by hipMemsetAsync
// on the stream (graph-capturable). r19 lesson: no Tri double-buffer
// (compiler caps this block shape at 128 VGPR; 2x45 Tri spills).
__global__ __launch_bounds__(BLK, 1)
void dev_serial(const float* __restrict__ x,
                const float* __restrict__ A,
                float* __restrict__ ws,
                float* __restrict__ out)
{
    __shared__ __align__(16) float skq_s[45 * SKST];    // 2160 B, e-major
    __shared__ __align__(16) float buf_s[SEGS * MATS];  // 47616 B tree buffer
    __shared__ int won_s;

    const int tid   = threadIdx.x;
    const int chain = blockIdx.x >> 1;   // / NCHK
    const int qt    = blockIdx.x & 1;
    const int n     = chain >> 1;        // / CC
    const int c     = chain & 1;

    // skq[e][ip] = sk-tri entry e of input dim ip (channel c). 360 entries.
    if (tid < 45 * 8) {
        const int e  = tid >> 3;
        const int ip = tid & 7;
        int k = 0, r2 = e;
        while (r2 >= 9 - k) { r2 -= (9 - k); ++k; }
        const int j = k + 1 + r2;
        const float* Ab = A + (size_t)(c * INQ + ip) * (MM * MM);
        skq_s[e * SKST + ip] = Ab[k * MM + j] - Ab[j * MM + k];
    }
    __syncthreads();

    const int wv  = tid >> 6;            // wave 0..7
    const int wl  = tid & 63;            // lane in wave
    const int g   = wl / 5;              // group 0..11 (12 = inactive tail)
    const int r   = wl - 5 * g;          // role 0..4 -> owns rows {2r, 2r+1}
    const bool act = (wl < 60);
    const int seg = wv * 12 + g;         // 0..95 active
    const int p0  = 2 * r;

    // Scratch: group slot (wv*12+g)*60 floats, overlaid on buf_s.
    // Inactive lanes (g==12) write to a shared dump slot (96) and read
    // whatever their aliased base holds -- garbage in, discarded out.
    float* scr  = &buf_s[seg * SCRS];
    float* scrw = act ? scr : &buf_s[96 * SCRS];

    v2f R01[MM];
    #pragma unroll
    for (int j = 0; j < MM; ++j)
        R01[j] = (v2f){ (j == p0) ? 1.0f : 0.0f, (j == p0 + 1) ? 1.0f : 0.0f };

    const float4* px = reinterpret_cast<const float4*>(x + (size_t)n * TT * INQ);
    const int t0 = qt * (SEGS * SLEN) + seg * SLEN;   // padded timeline, < 2112
    const float* srow = &skq_s[(9 * r) * SKST];

    #pragma unroll 1
    for (int s = 0; s < SLEN; ++s) {
        // Clamped fresh loads; pad steps (t >= 2047) give dx = 0 -> exp = I.
        const int t = t0 + s;
        const int tc = (t     > TT - 1) ? TT - 1 : t;
        const int t1 = (t + 1 > TT - 1) ? TT - 1 : t + 1;
        const float4 a0 = px[2 * tc], a1 = px[2 * tc + 1];
        const float4 b0 = px[2 * t1], b1 = px[2 * t1 + 1];
        float dx[INQ];
        dx[0] = b0.x - a0.x; dx[1] = b0.y - a0.y;
        dx[2] = b0.z - a0.z; dx[3] = b0.w - a0.w;
        dx[4] = b1.x - a1.x; dx[5] = b1.y - a1.y;
        dx[6] = b1.z - a1.z; dx[7] = b1.w - a1.w;

        // This lane's 9 tri entries: e = 9r+i, tvv[i] = dx . skq[e][:]
        float tvv[9];
        #pragma unroll
        for (int i = 0; i < 9; ++i) {
            const float4 s0 = *reinterpret_cast<const float4*>(srow + i * SKST);
            const float4 s1 = *reinterpret_cast<const float4*>(srow + i * SKST + 4);
            tvv[i] = dx[0] * s0.x + dx[1] * s0.y + dx[2] * s0.z + dx[3] * s0.w
                   + dx[4] * s1.x + dx[5] * s1.y + dx[6] * s1.z + dx[7] * s1.w;
        }

        // Stage to group scratch: 2 b128 + 1 b32 (lane slot 48B-aligned).
        *reinterpret_cast<float4*>(scrw + 12 * r)     = make_float4(tvv[0], tvv[1], tvv[2], tvv[3]);
        *reinterpret_cast<float4*>(scrw + 12 * r + 4) = make_float4(tvv[4], tvv[5], tvv[6], tvv[7]);
        scrw[12 * r + 8] = tvv[8];

        // Gather the group's 45: 5 x (b128, b128, b32). Same-wave LDS
        // ordering makes the RAW safe without a barrier.
        float Tri[45];
        #pragma unroll
        for (int q2 = 0; q2 < 5; ++q2) {
            const float4 u0 = *reinterpret_cast<const float4*>(scr + 12 * q2);
            const float4 u1 = *reinterpret_cast<const float4*>(scr + 12 * q2 + 4);
            const float  u2 = scr[12 * q2 + 8];
            Tri[9 * q2 + 0] = u0.x; Tri[9 * q2 + 1] = u0.y;
            Tri[9 * q2 + 2] = u0.z; Tri[9 * q2 + 3] = u0.w;
            Tri[9 * q2 + 4] = u1.x; Tri[9 * q2 + 5] = u1.y;
            Tri[9 * q2 + 6] = u1.z; Tri[9 * q2 + 7] = u1.w;
            Tri[9 * q2 + 8] = u2;
        }

        taylor5(Tri, R01);
    }

    // Scratch phase over; buf_s becomes the tree buffer.
    __syncthreads();

    // Store segment product: each active lane stores its pair of rows.
    if (act) {
        float* dst = &buf_s[seg * MATS];
        float4* d0 = reinterpret_cast<float4*>(dst + p0 * ROWP);
        d0[0] = make_float4(R01[0].x, R01[1].x, R01[2].x, R01[3].x);
        d0[1] = make_float4(R01[4].x, R01[5].x, R01[6].x, R01[7].x);
        d0[2] = make_float4(R01[8].x, R01[9].x, 0.0f, 0.0f);
        float4* d1 = reinterpret_cast<float4*>(dst + (p0 + 1) * ROWP);
        d1[0] = make_float4(R01[0].y, R01[1].y, R01[2].y, R01[3].y);
        d1[1] = make_float4(R01[4].y, R01[5].y, R01[6].y, R01[7].y);
        d1[2] = make_float4(R01[8].y, R01[9].y, 0.0f, 0.0f);
    }
    __syncthreads();

    // Dyadic tree on 96 leaves: spans 2..32 -> products at {0,32,64},
    // then (0*32) and (0*64) sequential tail (time order preserved).
    #pragma unroll 1
    for (int span = 2; span <= 32; span <<= 1) {
        const int np = SEGS / span;
        if (tid < 2 * np) {
            const int pr = tid >> 1;
            const int pq = tid & 1;
            pair_combine(buf_s, pr * span, pr * span + (span >> 1), pq);
        }
        __syncthreads();
    }
    if (tid < 2) pair_combine(buf_s, 0, 32, tid);
    __syncthreads();
    if (tid < 2) pair_combine(buf_s, 0, 64, tid);
    __syncthreads();

    // ---- Fused cross-block combine (replaces dev_tree2) ----
    // Publish this chunk's 120-float product via AGENT-scope atomics
    // (coherent across non-coherent XCD L2s).
    if (tid < 120)
        __hip_atomic_store(&ws[((size_t)chain * NCHK + qt) * 120 + tid], buf_s[tid],
                           __ATOMIC_RELAXED, __HIP_MEMORY_SCOPE_AGENT);
    __syncthreads();   // drains vmcnt -> stores complete before the flag

    int* flags = reinterpret_cast<int*>(ws + FLAGS_OFF_F);
    if (tid == 0)
        won_s = __hip_atomic_fetch_add(&flags[chain], 1,
                                       __ATOMIC_ACQ_REL, __HIP_MEMORY_SCOPE_AGENT);
    __syncthreads();
    if (won_s == 0) return;               // first arriver: done

    // Second arriver: load both chunk products, combine in time order.
    if (tid < 240) {
        const int m = tid / 120, f = tid - m * 120;
        buf_s[m * MATS + f] =
            __hip_atomic_load(&ws[((size_t)chain * NCHK + m) * 120 + f],
                              __ATOMIC_RELAXED, __HIP_MEMORY_SCOPE_AGENT);
    }
    __syncthreads();
    if (tid < 2) pair_combine(buf_s, 0, 1, tid);
    __syncthreads();
    if (tid < 100) {
        const int i = tid / 10;
        const int j = tid - i * 10;
        out[(size_t)chain * 100 + tid] = buf_s[i * ROWP + j];
    }
}

extern "C" void kernel_launch(void* const* d_in, const int* in_sizes, int n_in,
                              void* d_out, int out_size, void* d_ws, size_t ws_size,
                              hipStream_t stream) {
    (void)in_sizes; (void)n_in; (void)out_size; (void)ws_size;
    const float* x = (const float*)d_in[0];  // (64, 2048, 8)
    const float* A = (const float*)d_in[1];  // (2, 8, 10, 10)
    float* out = (float*)d_out;              // (64, 2, 10, 10)
    float* ws  = (float*)d_ws;               // products 122,880 B + flags 512 B

    // Zero the per-chain arrival flags (stream-ordered, graph-capturable).
    hipMemsetAsync((char*)d_ws + FLAGS_OFF_F * sizeof(float), 0,
                   NCHAIN * sizeof(int), stream);
    dev_serial<<<dim3(NCHAIN * NCHK), dim3(BLK), 0, stream>>>(x, A, ws, out);
}

// Round 9
// 94.646 us; speedup vs baseline: 1.8931x; 1.0214x over previous
//
#include <hip/hip_runtime.h>

// Problem constants
#define NB     64      // batch
#define TT     2048    // time
#define INQ    8       // input size
#define CC     2       // channels
#define MM     10      // hidden m
#define ROWP   12      // padded row floats (48 B)
#define MATS   124     // matrix stride in LDS tree (124%32=28)
#define SKST   12      // skq row stride floats (48 B, b128-aligned)
#define BLK    512     // threads per block (8 waves)
#define SEGS   96      // 8 waves * 12 five-lane groups
#define SLEN   11      // steps per segment (padded timeline 2112 = 2*96*11, 3% pad)
#define NCHK   2       // chunks per chain -> grid 256 = 1 block/CU
#define NCHAIN (NB*CC)
#define SLOT   120     // scratch slot floats per group (2 parities x 60)

typedef float v2f __attribute__((ext_vector_type(2)));

static_assert(SEGS * MATS >= 97 * SLOT, "scratch overlay must fit tree buffer");

// Upper-triangle index for (k,j), k<j, into 45-element array
__device__ __forceinline__ constexpr int triIdx(int k, int j) {
    return k * 10 + j - ((k + 1) * (k + 2)) / 2;
}

// One Taylor row-stream, packed pair of rows: t = S*G; A = t; R += cj*t.
// Row r of S*G depends only on row r of S -> in-place safe (S may alias A).
__device__ __forceinline__ void trow_pk(const float* __restrict__ Tri,
                                        v2f* A, v2f* R, const v2f* S, float cj) {
    v2f t[MM];
    t[0] = -S[1] * Tri[triIdx(0, 1)];
    #pragma unroll
    for (int j = 1; j < MM; ++j) t[j] = S[0] * Tri[triIdx(0, j)];
    #pragma unroll
    for (int k = 1; k < MM; ++k) {
        const v2f a = S[k];
        #pragma unroll
        for (int j = 0; j < MM; ++j) {
            if (k == j) continue;
            if (j == 0 && k == 1) continue;
            if (j > k) t[j] += a * Tri[triIdx(k, j)];
            else       t[j] -= a * Tri[triIdx(j, k)];
        }
    }
    #pragma unroll
    for (int j = 0; j < MM; ++j) { A[j] = t[j]; R[j] += cj * t[j]; }
}

// KTAY=5 Taylor burst on the packed row-pair accumulator.
__device__ __forceinline__ void taylor5(const float* __restrict__ Tri, v2f* R01) {
    __builtin_amdgcn_s_setprio(1);
    v2f A01[MM];
    trow_pk(Tri, A01, R01, R01, 1.0f);
    trow_pk(Tri, A01, R01, A01, 0.5f);
    trow_pk(Tri, A01, R01, A01, 0.16666667f);
    trow_pk(Tri, A01, R01, A01, 0.041666668f);
    trow_pk(Tri, A01, R01, A01, 0.0083333338f);
    __builtin_amdgcn_s_setprio(0);
}

// tvv for one step: clamped x loads, dx, 9 dot-products against skq rows.
__device__ __forceinline__ void compute_tvv(const float4* __restrict__ px, int t,
                                            const float* __restrict__ srow,
                                            float* __restrict__ tvv) {
    const int tc = (t     > TT - 1) ? TT - 1 : t;
    const int t1 = (t + 1 > TT - 1) ? TT - 1 : t + 1;
    const float4 a0 = px[2 * tc], a1 = px[2 * tc + 1];
    const float4 b0 = px[2 * t1], b1 = px[2 * t1 + 1];
    float dx[INQ];
    dx[0] = b0.x - a0.x; dx[1] = b0.y - a0.y;
    dx[2] = b0.z - a0.z; dx[3] = b0.w - a0.w;
    dx[4] = b1.x - a1.x; dx[5] = b1.y - a1.y;
    dx[6] = b1.z - a1.z; dx[7] = b1.w - a1.w;
    #pragma unroll
    for (int i = 0; i < 9; ++i) {
        const float4 s0 = *reinterpret_cast<const float4*>(srow + i * SKST);
        const float4 s1 = *reinterpret_cast<const float4*>(srow + i * SKST + 4);
        tvv[i] = dx[0] * s0.x + dx[1] * s0.y + dx[2] * s0.z + dx[3] * s0.w
               + dx[4] * s1.x + dx[5] * s1.y + dx[6] * s1.z + dx[7] * s1.w;
    }
}

// Stage 9 tvv to the group scratch slot: 2 b128 + 1 b32 (48B-aligned lane slot).
__device__ __forceinline__ void store_tvv(float* __restrict__ dst, int r,
                                          const float* __restrict__ tvv) {
    *reinterpret_cast<float4*>(dst + 12 * r)     = make_float4(tvv[0], tvv[1], tvv[2], tvv[3]);
    *reinterpret_cast<float4*>(dst + 12 * r + 4) = make_float4(tvv[4], tvv[5], tvv[6], tvv[7]);
    dst[12 * r + 8] = tvv[8];
}

// Gather the group's 45 entries: 5 x (b128, b128, b32).
__device__ __forceinline__ void load_tri(const float* __restrict__ src,
                                         float* __restrict__ Tri) {
    #pragma unroll
    for (int q2 = 0; q2 < 5; ++q2) {
        const float4 u0 = *reinterpret_cast<const float4*>(src + 12 * q2);
        const float4 u1 = *reinterpret_cast<const float4*>(src + 12 * q2 + 4);
        const float  u2 = src[12 * q2 + 8];
        Tri[9 * q2 + 0] = u0.x; Tri[9 * q2 + 1] = u0.y;
        Tri[9 * q2 + 2] = u0.z; Tri[9 * q2 + 3] = u0.w;
        Tri[9 * q2 + 4] = u1.x; Tri[9 * q2 + 5] = u1.y;
        Tri[9 * q2 + 6] = u1.z; Tri[9 * q2 + 7] = u1.w;
        Tri[9 * q2 + 8] = u2;
    }
}

// 2-lane pair combine: buf[ls] <- buf[ls] * buf[rs] (pq = which 5-row half)
__device__ __forceinline__ void pair_combine(float* buf_s, int ls, int rs, int pq) {
    float lrow[5][MM];
    #pragma unroll
    for (int r = 0; r < 5; ++r) {
        const float4* lr = reinterpret_cast<const float4*>(
            &buf_s[ls * MATS + (pq * 5 + r) * ROWP]);
        const float4 a = lr[0], b = lr[1], c4 = lr[2];
        lrow[r][0] = a.x;  lrow[r][1] = a.y;  lrow[r][2] = a.z;  lrow[r][3] = a.w;
        lrow[r][4] = b.x;  lrow[r][5] = b.y;  lrow[r][6] = b.z;  lrow[r][7] = b.w;
        lrow[r][8] = c4.x; lrow[r][9] = c4.y;
    }
    float d[5][MM];
    #pragma unroll
    for (int r = 0; r < 5; ++r)
        #pragma unroll
        for (int j = 0; j < MM; ++j)
            d[r][j] = 0.0f;
    #pragma unroll
    for (int k = 0; k < MM; ++k) {
        const float4* rr = reinterpret_cast<const float4*>(&buf_s[rs * MATS + k * ROWP]);
        const float4 a = rr[0], b = rr[1], c4 = rr[2];
        float rrow[MM];
        rrow[0] = a.x;  rrow[1] = a.y;  rrow[2] = a.z;  rrow[3] = a.w;
        rrow[4] = b.x;  rrow[5] = b.y;  rrow[6] = b.z;  rrow[7] = b.w;
        rrow[8] = c4.x; rrow[9] = c4.y;
        #pragma unroll
        for (int r = 0; r < 5; ++r) {
            const float lv = lrow[r][k];
            #pragma unroll
            for (int j = 0; j < MM; ++j)
                d[r][j] += lv * rrow[j];
        }
    }
    float* dst = &buf_s[ls * MATS + pq * 5 * ROWP];
    #pragma unroll
    for (int r = 0; r < 5; ++r) {
        float4* drow = reinterpret_cast<float4*>(dst + r * ROWP);
        drow[0] = make_float4(d[r][0], d[r][1], d[r][2], d[r][3]);
        drow[1] = make_float4(d[r][4], d[r][5], d[r][6], d[r][7]);
        drow[2] = make_float4(d[r][8], d[r][9], 0.0f, 0.0f);
    }
}

// r21: (1) REVERT r20's K2 fusion — measured tails: r18's second kernel
// cost 35.8 us total-minus-serial vs r20's memset+atomic-fusion 46.6 us;
// the fusion was an 11 us regression. Plain dev_tree2 returns. (2) Keep
// r20's LDS-op diet (serial 61.5->50.1, proven) and add the pipeline r19
// couldn't afford in registers: double-buffer the 60-float LDS scratch
// slot (97 x 120 floats = 46.6 KB, overlays buf_s) instead of the 45-reg
// Tri. Iteration order: read Tri(s) -> compute tvv(s+1) -> write slot
// (s+1 parity) -> taylor(s). The Tri read's ~120cy latency hides under
// the independent tvv compute; its data was written one full Taylor
// burst (~1100cy) earlier, so the write->read round-trip is never
// exposed. +9 VGPR (tvv lives across the read), peak ~115 < 128 cap.
// Math bit-identical to r18/r20 (pure reorder). Litmus: FETCH ~4.3 MB.
__global__ __launch_bounds__(BLK, 1)
void dev_serial(const float* __restrict__ x,
                const float* __restrict__ A,
                float* __restrict__ ws)
{
    __shared__ __align__(16) float skq_s[45 * SKST];    // 2160 B, e-major
    __shared__ __align__(16) float buf_s[SEGS * MATS];  // 47616 B tree buffer

    const int tid   = threadIdx.x;
    const int chain = blockIdx.x >> 1;   // / NCHK
    const int qt    = blockIdx.x & 1;
    const int n     = chain >> 1;        // / CC
    const int c     = chain & 1;

    // skq[e][ip] = sk-tri entry e of input dim ip (channel c). 360 entries.
    if (tid < 45 * 8) {
        const int e  = tid >> 3;
        const int ip = tid & 7;
        int k = 0, r2 = e;
        while (r2 >= 9 - k) { r2 -= (9 - k); ++k; }
        const int j = k + 1 + r2;
        const float* Ab = A + (size_t)(c * INQ + ip) * (MM * MM);
        skq_s[e * SKST + ip] = Ab[k * MM + j] - Ab[j * MM + k];
    }
    __syncthreads();

    const int wv  = tid >> 6;            // wave 0..7
    const int wl  = tid & 63;            // lane in wave
    const int g   = wl / 5;              // group 0..11 (12 = inactive tail)
    const int r   = wl - 5 * g;          // role 0..4 -> owns rows {2r, 2r+1}
    const bool act = (wl < 60);
    const int seg = wv * 12 + g;         // 0..95 active
    const int p0  = 2 * r;

    // Scratch slot (120 floats = 2 parities x 60), overlaid on buf_s.
    // Inactive lanes (g==12) write to dump slot 96; their reads alias the
    // next wave's slot 0 or the dump -- garbage in, discarded out.
    float* slot  = &buf_s[seg * SLOT];
    float* slotw = act ? slot : &buf_s[96 * SLOT];

    v2f R01[MM];
    #pragma unroll
    for (int j = 0; j < MM; ++j)
        R01[j] = (v2f){ (j == p0) ? 1.0f : 0.0f, (j == p0 + 1) ? 1.0f : 0.0f };

    const float4* px = reinterpret_cast<const float4*>(x + (size_t)n * TT * INQ);
    const int t0 = qt * (SEGS * SLEN) + seg * SLEN;   // padded timeline, < 2112
    const float* srow = &skq_s[(9 * r) * SKST];

    // Software pipeline over the scratch double-buffer.
    float tvv[9];
    compute_tvv(px, t0, srow, tvv);
    store_tvv(slotw, r, tvv);            // parity 0

    #pragma unroll 1
    for (int s = 0; s < SLEN - 1; ++s) {
        const int rpar = (s & 1) * 60;
        float Tri[45];
        load_tri(slot + rpar, Tri);            // data written 1 burst ago
        compute_tvv(px, t0 + s + 1, srow, tvv); // hides the read latency
        store_tvv(slotw + (60 - rpar), r, tvv); // opposite parity
        taylor5(Tri, R01);
    }
    {
        float Tri[45];
        load_tri(slot + ((SLEN - 1) & 1) * 60, Tri);
        taylor5(Tri, R01);
    }

    // Scratch phase over; buf_s becomes the tree buffer.
    __syncthreads();

    // Store segment product: each active lane stores its pair of rows.
    if (act) {
        float* dst = &buf_s[seg * MATS];
        float4* d0 = reinterpret_cast<float4*>(dst + p0 * ROWP);
        d0[0] = make_float4(R01[0].x, R01[1].x, R01[2].x, R01[3].x);
        d0[1] = make_float4(R01[4].x, R01[5].x, R01[6].x, R01[7].x);
        d0[2] = make_float4(R01[8].x, R01[9].x, 0.0f, 0.0f);
        float4* d1 = reinterpret_cast<float4*>(dst + (p0 + 1) * ROWP);
        d1[0] = make_float4(R01[0].y, R01[1].y, R01[2].y, R01[3].y);
        d1[1] = make_float4(R01[4].y, R01[5].y, R01[6].y, R01[7].y);
        d1[2] = make_float4(R01[8].y, R01[9].y, 0.0f, 0.0f);
    }
    __syncthreads();

    // Dyadic tree on 96 leaves: spans 2..32 -> products at {0,32,64},
    // then (0*32) and (0*64) sequential tail (time order preserved).
    #pragma unroll 1
    for (int span = 2; span <= 32; span <<= 1) {
        const int np = SEGS / span;
        if (tid < 2 * np) {
            const int pr = tid >> 1;
            const int pq = tid & 1;
            pair_combine(buf_s, pr * span, pr * span + (span >> 1), pq);
        }
        __syncthreads();
    }
    if (tid < 2) pair_combine(buf_s, 0, 32, tid);
    __syncthreads();
    if (tid < 2) pair_combine(buf_s, 0, 64, tid);
    __syncthreads();

    // Chunk product -> ws, padded 120 floats at (chain*NCHK + qt)
    if (tid < 30) {
        const float4 v = reinterpret_cast<const float4*>(buf_s)[tid];
        reinterpret_cast<float4*>(ws)[((size_t)chain * NCHK + qt) * 30 + tid] = v;
    }
}

// K2: one block per chain; combine its 2 chunk products (time order)
__global__ __launch_bounds__(256)
void dev_tree2(const float* __restrict__ ws, float* __restrict__ out)
{
    __shared__ __align__(16) float buf_s[2 * MATS];
    const int tid   = threadIdx.x;
    const int chain = blockIdx.x;

    if (tid < 60) {
        const int m  = tid / 30;
        const int o4 = tid - m * 30;
        const float4 v = reinterpret_cast<const float4*>(ws)[((size_t)chain * 2 + m) * 30 + o4];
        reinterpret_cast<float4*>(&buf_s[m * MATS])[o4] = v;
    }
    __syncthreads();

    if (tid < 2)
        pair_combine(buf_s, 0, 1, tid);
    __syncthreads();

    if (tid < 100) {
        const int i = tid / 10;
        const int j = tid - i * 10;
        out[(size_t)chain * 100 + tid] = buf_s[i * ROWP + j];
    }
}

extern "C" void kernel_launch(void* const* d_in, const int* in_sizes, int n_in,
                              void* d_out, int out_size, void* d_ws, size_t ws_size,
                              hipStream_t stream) {
    (void)in_sizes; (void)n_in; (void)out_size; (void)ws_size;
    const float* x = (const float*)d_in[0];  // (64, 2048, 8)
    const float* A = (const float*)d_in[1];  // (2, 8, 10, 10)
    float* out = (float*)d_out;              // (64, 2, 10, 10)
    float* ws  = (float*)d_ws;               // 256 mats * 480 B = 122,880 B

    dev_serial<<<dim3(NCHAIN * NCHK), dim3(BLK), 0, stream>>>(x, A, ws);
    dev_tree2<<<dim3(NCHAIN), dim3(256), 0, stream>>>(ws, out);
}